// Round 7
// baseline (500.044 us; speedup 1.0000x reference)
//
#include <hip/hip_runtime.h>

#define N_NODES 131072
#define MAXL 4096
#define NP 8

typedef __attribute__((ext_vector_type(8))) short bf16x8;
typedef __attribute__((ext_vector_type(4))) float f32x4;

// ws float offsets
#define OFF_QW     0u          // 64*256   folded (Q@WK)/16
#define OFF_QO     16384u      // 64*256   Q@WO^T
#define OFF_WF     32768u      // 256*256  WO@WV
#define OFF_QB     98304u      // 64
#define OFF_BVO    98368u      // 256
#define OFF_STARTS 98624u      // 65 ints (padded)
#define OFF_ASUM   98752u      // 64*64
#define OFF_Q      102848u     // 64*256
#define OFF_WQT    119232u     // 256*256
#define OFF_WOT    184768u     // 256*256
#define OFF_GP     250304u     // 8 * 64 * 16384  (end = 8638912 floats = 34.6 MB)

__device__ __forceinline__ unsigned short f2bf(float f) {
  union { float f; unsigned int u; } v; v.f = f;
  unsigned int u = v.u + 0x7FFFu + ((v.u >> 16) & 1u);  // RNE
  return (unsigned short)(u >> 16);
}

// DPP / swizzle lane-moves (value from lane^1 / lane^2 / lane^4 / lane^8)
__device__ __forceinline__ float dppx1(float v) {
  return __int_as_float(__builtin_amdgcn_update_dpp(0, __float_as_int(v), 0xB1, 0xF, 0xF, true));
}
__device__ __forceinline__ float dppx2(float v) {
  return __int_as_float(__builtin_amdgcn_update_dpp(0, __float_as_int(v), 0x4E, 0xF, 0xF, true));
}
__device__ __forceinline__ float swzx4(float v) {
  return __int_as_float(__builtin_amdgcn_ds_swizzle(__float_as_int(v), 0x101F));
}
__device__ __forceinline__ float swzx8(float v) {
  return __int_as_float(__builtin_amdgcn_ds_swizzle(__float_as_int(v), 0x201F));
}
// full butterfly sum over 8 lanes (used for asum only)
__device__ __forceinline__ float kq_sum(float v) {
  v += dppx1(v); v += dppx2(v); v += swzx4(v); return v;
}
// staged merge: keep own value (by sel), add partner's copy of the same value
__device__ __forceinline__ float mrg1(float u, float v, bool sel) {
  float snd = sel ? u : v, kp = sel ? v : u; return kp + dppx1(snd);
}
__device__ __forceinline__ float mrg2(float u, float v, bool sel) {
  float snd = sel ? u : v, kp = sel ? v : u; return kp + dppx2(snd);
}
__device__ __forceinline__ float mrg4(float u, float v, bool sel) {
  float snd = sel ? u : v, kp = sel ? v : u; return kp + swzx4(snd);
}
__device__ __forceinline__ float mrg8(float u, float v, bool sel) {
  float snd = sel ? u : v, kp = sel ? v : u; return kp + swzx8(snd);
}

// ---------------- setup ----------------

// transpose WQ_w (z=0) and WO_w (z=1) into WQT / WOT
__global__ __launch_bounds__(256) void k_tr(const float* __restrict__ WQ_w,
    const float* __restrict__ WO_w, float* __restrict__ WQT, float* __restrict__ WOT)
{
  __shared__ float tile[32][33];
  const float* src = blockIdx.z ? WO_w : WQ_w;
  float* dst = blockIdx.z ? WOT : WQT;
  const int bx = blockIdx.x * 32, by = blockIdx.y * 32;
  const int tx = threadIdx.x & 31, ty = threadIdx.x >> 5;
  #pragma unroll
  for (int i = 0; i < 4; ++i)
    tile[ty + 8 * i][tx] = src[(size_t)(by + ty + 8 * i) * 256 + bx + tx];
  __syncthreads();
  #pragma unroll
  for (int i = 0; i < 4; ++i)
    dst[(size_t)(bx + ty + 8 * i) * 256 + by + tx] = tile[tx][ty + 8 * i];
}

// Q[c][d] = sum_k Qp[c][k] * WQT[k][d] + WQ_b[d]   (K split over 4 groups)
__global__ __launch_bounds__(1024) void k_q(const float* __restrict__ Qp,
    const float* __restrict__ WQT, const float* __restrict__ WQ_b,
    float* __restrict__ Q)
{
  __shared__ float red[4][256];
  const int c = blockIdx.x, t = threadIdx.x;
  const int d = t & 255, kk = t >> 8;
  float acc = 0.f;
  #pragma unroll 4
  for (int k = kk * 64; k < kk * 64 + 64; ++k)
    acc += Qp[c * 256 + k] * WQT[k * 256 + d];
  red[kk][d] = acc;
  __syncthreads();
  if (kk == 0)
    Q[c * 256 + d] = red[0][d] + red[1][d] + red[2][d] + red[3][d] + WQ_b[d];
}

// QW = (Q@WK)/16 (fp64 acc), QO = Q@WO^T, qb = (Q@WK_b)/16 (K split over 4)
__global__ __launch_bounds__(1024) void k_fold(const float* __restrict__ Q,
    const float* __restrict__ WK_w, const float* __restrict__ WK_b,
    const float* __restrict__ WOT,
    float* __restrict__ QW, float* __restrict__ QO, float* __restrict__ qb)
{
  __shared__ float Qrow[256];
  __shared__ double redw[4][256];
  __shared__ float redo[4][256];
  const int c = blockIdx.x, t = threadIdx.x;
  const int d = t & 255, kk = t >> 8;
  if (t < 256) Qrow[t] = Q[c * 256 + t];
  __syncthreads();
  double aqw = 0.0;
  float aqo = 0.f;
  #pragma unroll 4
  for (int j = kk * 64; j < kk * 64 + 64; ++j) {
    float qcj = Qrow[j];
    aqw += (double)qcj * (double)WK_w[j * 256 + d];   // coalesced
    aqo += qcj * WOT[j * 256 + d];                    // coalesced
  }
  redw[kk][d] = aqw;
  redo[kk][d] = aqo;
  __syncthreads();
  if (kk == 0) {
    QW[c * 256 + d] = (float)((redw[0][d] + redw[1][d] + redw[2][d] + redw[3][d]) * 0.0625);
    QO[c * 256 + d] = redo[0][d] + redo[1][d] + redo[2][d] + redo[3][d];
  }
  __syncthreads();
  if (t < 256) redw[0][t] = (double)Qrow[t] * (double)WK_b[t];
  __syncthreads();
  for (int sft = 128; sft >= 1; sft >>= 1) {
    if (t < sft) redw[0][t] += redw[0][t + sft];
    __syncthreads();
  }
  if (t == 0) qb[c] = (float)(redw[0][0] * 0.0625);
}

// Wf[i][d] = sum_j WO_w[i][j]*WV_w[j][d]; bvo[i] = sum_j WV_b[j]*WO_w[i][j]
__global__ __launch_bounds__(1024) void k_wf(const float* __restrict__ WO_w,
    const float* __restrict__ WV_w, const float* __restrict__ WV_b,
    float* __restrict__ Wf, float* __restrict__ bvo)
{
  __shared__ float red[4][256];
  __shared__ float redb[4];
  const int i = blockIdx.x, t = threadIdx.x;
  const int d = t & 255, kk = t >> 8;
  float acc = 0.f;
  #pragma unroll 4
  for (int j = kk * 64; j < kk * 64 + 64; ++j)
    acc += WO_w[i * 256 + j] * WV_w[j * 256 + d];  // WO scalar, WV coalesced
  red[kk][d] = acc;
  if (d == 0) {
    float s = 0.f;
    for (int j = kk * 64; j < kk * 64 + 64; ++j) s += WV_b[j] * WO_w[i * 256 + j];
    redb[kk] = s;
  }
  __syncthreads();
  if (kk == 0) {
    Wf[i * 256 + d] = red[0][d] + red[1][d] + red[2][d] + red[3][d];
    if (d == 0) bvo[i] = redb[0] + redb[1] + redb[2] + redb[3];
  }
}

__global__ void k_starts(const int* __restrict__ batch, int* __restrict__ starts)
{
  int t = threadIdx.x;
  if (t > 64) return;
  if (t == 0) { starts[0] = 0; return; }
  if (t == 64) { starts[64] = N_NODES; return; }
  int lo = 0, hi = N_NODES;
  while (lo < hi) {
    int mid = (lo + hi) >> 1;
    if (batch[mid] < t) lo = mid + 1; else hi = mid;
  }
  starts[t] = lo;
}

// ---------------- fused: scores + softmax + argmax/mask + G (MFMA) ----------
// grid (NP, 64 graphs), 512 threads (8 waves), chunk = 32 nodes.
// Round-6 structure with the score phase remapped to (cp2 = lane>>4,
// kq2 = lane&15): each thread owns 4 clusters (c = wg*16 + cp2 + 4j) and a
// 16-float k-slice, so each ds_read_b128 of xv feeds 16 FMAs (was 8) and
// score LDS reads halve (128 -> 64 per thread per chunk). Round 3 vs round 6
// showed dur invariant under 2x occupancy => bound by a shared per-CU
// throughput resource; LDS pipe is the largest modeled consumer.
// Reduce over 16 lanes: staged merge xor1(n0)/xor2(n1) via DPP,
// xor4(j0)/xor8(j1) via ds_swizzle; lane kq2 ends with (n = kq2&3,
// j = (kq2>>2)&3), written to ss[wh*16 + sub*4 + (kq2&3)][cW] (wh included!).
// All other phases byte-identical to round 6 (passed, absmax 0.03125).

__global__ __launch_bounds__(512, 4) void k_fused(
    const float* __restrict__ x, const int* __restrict__ starts,
    const float* __restrict__ qw, const float* __restrict__ qbv,
    float* __restrict__ Gp, float* __restrict__ asum,
    float* __restrict__ out_arg, float* __restrict__ out_msk)
{
  __shared__ float xs[32][256];                        // fp32 chunk, col-swizzled
  __shared__ float ss[32][68];                         // scores [n][c]
  __shared__ float stats_m[32], stats_i[32];
  __shared__ __align__(16) unsigned short As[64][40];  // a bf16 [c][n]
  __shared__ __align__(16) unsigned short XsT[256][40];// x bf16 transposed [d][n]

  const int t = threadIdx.x;
  const int p = blockIdx.x, b = blockIdx.y;
  const int s0 = starts[b], s1 = starts[b + 1];
  const int w = t >> 6, lane = t & 63;
  const int wg = w & 3, wh = w >> 2;
  const int cp = lane >> 3, kq = lane & 7;             // a-phase mapping (old)
  const int c0 = wg * 16 + cp, c1 = c0 + 8;

  const float qb0 = qbv[c0], qb1 = qbv[c1];

  // score-phase mapping: 4 clusters/thread, 16-float k-slice
  const int cp2 = lane >> 4, kq2 = lane & 15;
  const bool m1 = kq2 & 1, m2 = kq2 & 2, m4 = kq2 & 4, m8 = kq2 & 8;
  const int cW = wg * 16 + cp2 + 4 * ((kq2 >> 2) & 3); // cluster this lane writes
  const float qbW = qbv[cW];
  const float* qj0 = qw + (size_t)(wg * 16 + cp2 +  0) * 256 + kq2 * 16;
  const float* qj1 = qw + (size_t)(wg * 16 + cp2 +  4) * 256 + kq2 * 16;
  const float* qj2 = qw + (size_t)(wg * 16 + cp2 +  8) * 256 + kq2 * 16;
  const float* qj3 = qw + (size_t)(wg * 16 + cp2 + 12) * 256 + kq2 * 16;

  f32x4 gacc[8];
  #pragma unroll
  for (int i = 0; i < 8; ++i) gacc[i] = (f32x4){0.f, 0.f, 0.f, 0.f};
  float asv0 = 0.f, asv1 = 0.f;

  const int stcol = (lane * 4) ^ (4 * ((lane >> 3) & 7));  // staging store column
  const int dX = t & 255, hX = t >> 8;                     // XsT-fill mapping
  const int dsz = dX ^ (4 * ((dX >> 5) & 7));              // swizzled read column

  #pragma unroll 1
  for (int base = s0 + p * 32; base < s1; base += NP * 32) {
    // ---- stage x chunk: wave w covers rows 4w..4w+3 (coalesced 1KB/row)
    #pragma unroll
    for (int i = 0; i < 4; ++i) {
      int r = w * 4 + i;
      int gr = base + r; if (gr >= s1) gr = s1 - 1;
      float4 v = *(const float4*)&x[(size_t)gr * 256 + lane * 4];
      *(float4*)&xs[r][stcol] = v;
    }
    __syncthreads();
    // ---- XsT fill: 2 threads/column; thread packs rows hX*16..hX*16+15
    #pragma unroll
    for (int g = 0; g < 4; ++g) {
      const int r0 = hX * 16 + g * 4;
      ushort4 pk;
      pk.x = f2bf(xs[r0 + 0][dsz]);
      pk.y = f2bf(xs[r0 + 1][dsz]);
      pk.z = f2bf(xs[r0 + 2][dsz]);
      pk.w = f2bf(xs[r0 + 3][dsz]);
      *(ushort4*)&XsT[dX][r0] = pk;
    }
    // ---- scores: wave-half wh covers nodes wh*16..wh*16+15, 4 sub-blocks of 4
    #pragma unroll 1
    for (int sub = 0; sub < 4; ++sub) {
      float a0[4], a1[4], a2[4], a3[4];
      #pragma unroll
      for (int n = 0; n < 4; ++n) { a0[n] = 0.f; a1[n] = 0.f; a2[n] = 0.f; a3[n] = 0.f; }
      const float* xb = &xs[wh * 16 + sub * 4][0];
      #pragma unroll 1
      for (int kk = 0; kk < 4; ++kk) {
        float4 q0 = *(const float4*)&qj0[kk * 4];
        float4 q1 = *(const float4*)&qj1[kk * 4];
        float4 q2 = *(const float4*)&qj2[kk * 4];
        float4 q3 = *(const float4*)&qj3[kk * 4];
        const int colb = kq2 * 16 + kk * 4;
        const int col = colb ^ (4 * ((colb >> 5) & 7));
        #pragma unroll
        for (int n = 0; n < 4; ++n) {
          float4 xv = *(const float4*)&xb[n * 256 + col];
          a0[n] = fmaf(q0.w, xv.w, fmaf(q0.z, xv.z, fmaf(q0.y, xv.y, fmaf(q0.x, xv.x, a0[n]))));
          a1[n] = fmaf(q1.w, xv.w, fmaf(q1.z, xv.z, fmaf(q1.y, xv.y, fmaf(q1.x, xv.x, a1[n]))));
          a2[n] = fmaf(q2.w, xv.w, fmaf(q2.z, xv.z, fmaf(q2.y, xv.y, fmaf(q2.x, xv.x, a2[n]))));
          a3[n] = fmaf(q3.w, xv.w, fmaf(q3.z, xv.z, fmaf(q3.y, xv.y, fmaf(q3.x, xv.x, a3[n]))));
        }
      }
      // staged 16-lane reduce: xor1->n bit0, xor2->n bit1, xor4->j bit0,
      // xor8->j bit1. Lane kq2 ends with (n = kq2&3, j = (kq2>>2)&3) = cW.
      {
        float r0 = mrg1(a0[0], a0[1], m1);
        float r1 = mrg1(a0[2], a0[3], m1);
        float r2 = mrg1(a1[0], a1[1], m1);
        float r3 = mrg1(a1[2], a1[3], m1);
        float r4 = mrg1(a2[0], a2[1], m1);
        float r5 = mrg1(a2[2], a2[3], m1);
        float r6 = mrg1(a3[0], a3[1], m1);
        float r7 = mrg1(a3[2], a3[3], m1);
        float sA = mrg2(r0, r1, m2);   // j=0
        float sB = mrg2(r2, r3, m2);   // j=1
        float sC = mrg2(r4, r5, m2);   // j=2
        float sD = mrg2(r6, r7, m2);   // j=3
        float u0 = mrg4(sA, sB, m4);   // j in {0,1}
        float u1 = mrg4(sC, sD, m4);   // j in {2,3}
        float val = mrg8(u0, u1, m8);
        const int nn = wh * 16 + sub * 4 + (kq2 & 3);   // wh*16 included!
        ss[nn][cW] = val + qbW;
      }
    }
    __syncthreads();
    // ---- softmax stats + argmax: threads 0..255, 8 threads/node
    if (t < 256) {
      const int nn = t >> 3, oct = t & 7;
      float v8[8];
      #pragma unroll
      for (int u = 0; u < 8; ++u) v8[u] = ss[nn][oct * 8 + u];
      float m = v8[0]; int am = oct * 8;
      #pragma unroll
      for (int u = 1; u < 8; ++u)
        if (v8[u] > m) { m = v8[u]; am = oct * 8 + u; }   // strict >: first max
      #pragma unroll
      for (int d = 1; d < 8; d <<= 1) {
        float mo = __shfl_xor(m, d);
        int ao = __shfl_xor(am, d);
        if (mo > m || (mo == m && ao < am)) { m = mo; am = ao; }
      }
      float s = 0.f;
      #pragma unroll
      for (int u = 0; u < 8; ++u) s += __expf(v8[u] - m);
      #pragma unroll
      for (int d = 1; d < 8; d <<= 1) s += __shfl_xor(s, d);
      if (oct == 0) {
        stats_m[nn] = m;
        stats_i[nn] = 1.f / s;
        int n = base + nn;
        if (n < s1) {
          int pos = n - s0;
          out_arg[(size_t)b * MAXL + pos] = (float)am;
          out_msk[(size_t)b * MAXL + pos] = 1.0f;
        }
      }
    }
    __syncthreads();
    // ---- a-values -> As (bf16) + asum; thread covers n = 4kq+2wh+{0,1}
    {
      unsigned short pb0[2], pb1[2];
      #pragma unroll
      for (int i = 0; i < 2; ++i) {
        int nn = 4 * kq + 2 * wh + i;
        bool valid = (base + nn) < s1;
        float m = stats_m[nn], inv = stats_i[nn];
        float av0 = valid ? __expf(ss[nn][c0] - m) * inv : 0.f;
        float av1 = valid ? __expf(ss[nn][c1] - m) * inv : 0.f;
        asv0 += av0; asv1 += av1;
        pb0[i] = f2bf(av0);
        pb1[i] = f2bf(av1);
      }
      *(ushort2*)&As[c0][4 * kq + 2 * wh] = *(const ushort2*)pb0;
      *(ushort2*)&As[c1][4 * kq + 2 * wh] = *(const ushort2*)pb1;
    }
    __syncthreads();
    // ---- G MFMA: wave handles clusters 16wg..16wg+15, dt half wh*8..wh*8+7
    {
      const int q = lane >> 4, mm = lane & 15;
      bf16x8 afrag = *(const bf16x8*)&As[16 * wg + mm][q * 8];
      #pragma unroll
      for (int dt2 = 0; dt2 < 8; ++dt2) {
        const int dt = wh * 8 + dt2;
        bf16x8 bfrag = *(const bf16x8*)&XsT[16 * dt + mm][q * 8];
        gacc[dt2] = __builtin_amdgcn_mfma_f32_16x16x32_bf16(afrag, bfrag, gacc[dt2], 0, 0, 0);
      }
    }
    __syncthreads();
  }

  // ---- epilogue: store G slab (D layout: row=4*(lane>>4)+r, col=lane&15)
  {
    float* g = Gp + ((size_t)p * 64 + b) * 16384;
    const int q = lane >> 4, mm = lane & 15;
    #pragma unroll
    for (int dt2 = 0; dt2 < 8; ++dt2) {
      const int dt = wh * 8 + dt2;
      #pragma unroll
      for (int r = 0; r < 4; ++r)
        g[(size_t)(16 * wg + q * 4 + r) * 256 + 16 * dt + mm] = gacc[dt2][r];
    }
  }
  // asum: reduce per-thread partials over kq, one atomic per cluster per wh
  asv0 = kq_sum(asv0);
  asv1 = kq_sum(asv1);
  if (kq == 0) {
    atomicAdd(&asum[b * 64 + c0], asv0);
    atomicAdd(&asum[b * 64 + c1], asv1);
  }
}

// ---------------- finalize: out = relu(qo + (sum_p Gp)@Wf^T + asum*bvo + b) --

__global__ __launch_bounds__(256) void k_final(const float* __restrict__ Gp,
    int npart, const float* __restrict__ Wf, const float* __restrict__ qo,
    const float* __restrict__ asum, const float* __restrict__ bvo,
    const float* __restrict__ WO_b, float* __restrict__ out)
{
  __shared__ float gs[64 * 68];
  __shared__ float wfs[64 * 68];
  const int t = threadIdx.x;
  const int b = blockIdx.x >> 2;
  const int is = (blockIdx.x & 3) * 64;
  const int tx = t & 15, ty = t >> 4;
  const int sr = t >> 4, sq = t & 15;

  float acc[4][4];
  #pragma unroll
  for (int j = 0; j < 4; ++j)
    #pragma unroll
    for (int u = 0; u < 4; ++u) acc[j][u] = 0.f;

  for (int kc = 0; kc < 4; ++kc) {
    const int k0 = kc * 64;
    #pragma unroll
    for (int u = 0; u < 4; ++u) {
      int row = sr + 16 * u;
      float4 g = make_float4(0.f, 0.f, 0.f, 0.f);
      for (int p = 0; p < npart; ++p) {
        float4 gv = *(const float4*)&Gp[((size_t)p * 64 + b) * 16384
                                        + row * 256 + k0 + sq * 4];
        g.x += gv.x; g.y += gv.y; g.z += gv.z; g.w += gv.w;
      }
      *(float4*)&gs[row * 68 + sq * 4] = g;
      *(float4*)&wfs[row * 68 + sq * 4] =
          *(const float4*)&Wf[(size_t)(is + row) * 256 + k0 + sq * 4];
    }
    __syncthreads();
    #pragma unroll
    for (int k4 = 0; k4 < 16; ++k4) {
      float4 gr[4], wr[4];
      #pragma unroll
      for (int j = 0; j < 4; ++j) gr[j] = *(const float4*)&gs[(ty + 16 * j) * 68 + k4 * 4];
      #pragma unroll
      for (int u = 0; u < 4; ++u) wr[u] = *(const float4*)&wfs[(tx + 16 * u) * 68 + k4 * 4];
      #pragma unroll
      for (int j = 0; j < 4; ++j)
        #pragma unroll
        for (int u = 0; u < 4; ++u)
          acc[j][u] += gr[j].x * wr[u].x + gr[j].y * wr[u].y
                     + gr[j].z * wr[u].z + gr[j].w * wr[u].w;
    }
    __syncthreads();
  }

  #pragma unroll
  for (int j = 0; j < 4; ++j)
    #pragma unroll
    for (int u = 0; u < 4; ++u) {
      int cc = ty + 16 * j, i = is + tx + 16 * u;
      float v = acc[j][u] + qo[cc * 256 + i] + asum[b * 64 + cc] * bvo[i] + WO_b[i];
      out[(size_t)b * 16384 + cc * 256 + i] = fmaxf(v, 0.f);
    }
}

// ---------------- launch ----------------

extern "C" void kernel_launch(void* const* d_in, const int* in_sizes, int n_in,
                              void* d_out, int out_size, void* d_ws, size_t ws_size,
                              hipStream_t stream) {
  const float* x    = (const float*)d_in[0];
  const int*   batch= (const int*)d_in[1];
  const float* Qp   = (const float*)d_in[2];
  const float* WQ_w = (const float*)d_in[3];
  const float* WQ_b = (const float*)d_in[4];
  const float* WK_w = (const float*)d_in[5];
  const float* WK_b = (const float*)d_in[6];
  const float* WV_w = (const float*)d_in[7];
  const float* WV_b = (const float*)d_in[8];
  const float* WO_w = (const float*)d_in[9];
  const float* WO_b = (const float*)d_in[10];

  float* ws   = (float*)d_ws;
  float* QW   = ws + OFF_QW;
  float* QO   = ws + OFF_QO;
  float* Wf   = ws + OFF_WF;
  float* qb   = ws + OFF_QB;
  float* bvo  = ws + OFF_BVO;
  int*   starts = (int*)(ws + OFF_STARTS);
  float* asum = ws + OFF_ASUM;
  float* Q    = ws + OFF_Q;
  float* WQT  = ws + OFF_WQT;
  float* WOT  = ws + OFF_WOT;
  float* Gp   = ws + OFF_GP;

  float* out     = (float*)d_out;                 // [64][64][256]
  float* out_arg = out + 64 * 64 * 256;           // [64][4096]
  float* out_msk = out_arg + 64 * MAXL;           // [64][4096]

  hipMemsetAsync(asum, 0, 64 * 64 * sizeof(float), stream);
  hipMemsetAsync(out_arg, 0, (size_t)2 * 64 * MAXL * sizeof(float), stream);

  k_tr<<<dim3(8, 8, 2), 256, 0, stream>>>(WQ_w, WO_w, WQT, WOT);
  k_wf<<<256, 1024, 0, stream>>>(WO_w, WV_w, WV_b, Wf, bvo);
  k_starts<<<1, 128, 0, stream>>>(batch, starts);
  k_q<<<64, 1024, 0, stream>>>(Qp, WQT, WQ_b, Q);
  k_fold<<<64, 1024, 0, stream>>>(Q, WK_w, WK_b, WOT, QW, QO, qb);

  k_fused<<<dim3(NP, 64), 512, 0, stream>>>(x, starts, QW, qb, Gp, asum,
                                            out_arg, out_msk);
  k_final<<<64 * 4, 256, 0, stream>>>(Gp, NP, Wf, QO, asum, bvo, WO_b, out);
}

// Round 8
// 420.428 us; speedup vs baseline: 1.1894x; 1.1894x over previous
//
#include <hip/hip_runtime.h>

#define N_NODES 131072
#define MAXL 4096
#define NP 8

typedef __attribute__((ext_vector_type(8))) short bf16x8;
typedef __attribute__((ext_vector_type(4))) float f32x4;

// ws float offsets
#define OFF_QW     0u          // 64*256   folded (Q@WK)/16
#define OFF_QO     16384u      // 64*256   Q@WO^T
#define OFF_WF     32768u      // 256*256  WO@WV
#define OFF_QB     98304u      // 64
#define OFF_BVO    98368u      // 256
#define OFF_STARTS 98624u      // 65 ints (padded)
#define OFF_ASUM   98752u      // 64*64
#define OFF_Q      102848u     // 64*256
#define OFF_WQT    119232u     // 256*256
#define OFF_WOT    184768u     // 256*256
#define OFF_GP     250304u     // 8 * 64 * 16384  (end = 8638912 floats = 34.6 MB)

__device__ __forceinline__ unsigned short f2bf(float f) {
  union { float f; unsigned int u; } v; v.f = f;
  unsigned int u = v.u + 0x7FFFu + ((v.u >> 16) & 1u);  // RNE
  return (unsigned short)(u >> 16);
}

// DPP / swizzle lane-moves (value from lane^1 / lane^2 / lane^4)
__device__ __forceinline__ float dppx1(float v) {
  return __int_as_float(__builtin_amdgcn_update_dpp(0, __float_as_int(v), 0xB1, 0xF, 0xF, true));
}
__device__ __forceinline__ float dppx2(float v) {
  return __int_as_float(__builtin_amdgcn_update_dpp(0, __float_as_int(v), 0x4E, 0xF, 0xF, true));
}
__device__ __forceinline__ float swzx4(float v) {
  return __int_as_float(__builtin_amdgcn_ds_swizzle(__float_as_int(v), 0x101F));
}
// full butterfly sum over 8 lanes (used for asum only)
__device__ __forceinline__ float kq_sum(float v) {
  v += dppx1(v); v += dppx2(v); v += swzx4(v); return v;
}
// staged merge: keep own value (by sel), add partner's copy of the other
__device__ __forceinline__ float mrg1(float u, float v, bool sel) {
  float snd = sel ? u : v, kp = sel ? v : u; return kp + dppx1(snd);
}
__device__ __forceinline__ float mrg2(float u, float v, bool sel) {
  float snd = sel ? u : v, kp = sel ? v : u; return kp + dppx2(snd);
}
__device__ __forceinline__ float mrg4(float u, float v, bool sel) {
  float snd = sel ? u : v, kp = sel ? v : u; return kp + swzx4(snd);
}

// ---------------- setup ----------------

// transpose WQ_w (z=0) and WO_w (z=1) into WQT / WOT
__global__ __launch_bounds__(256) void k_tr(const float* __restrict__ WQ_w,
    const float* __restrict__ WO_w, float* __restrict__ WQT, float* __restrict__ WOT)
{
  __shared__ float tile[32][33];
  const float* src = blockIdx.z ? WO_w : WQ_w;
  float* dst = blockIdx.z ? WOT : WQT;
  const int bx = blockIdx.x * 32, by = blockIdx.y * 32;
  const int tx = threadIdx.x & 31, ty = threadIdx.x >> 5;
  #pragma unroll
  for (int i = 0; i < 4; ++i)
    tile[ty + 8 * i][tx] = src[(size_t)(by + ty + 8 * i) * 256 + bx + tx];
  __syncthreads();
  #pragma unroll
  for (int i = 0; i < 4; ++i)
    dst[(size_t)(bx + ty + 8 * i) * 256 + by + tx] = tile[tx][ty + 8 * i];
}

// Q[c][d] = sum_k Qp[c][k] * WQT[k][d] + WQ_b[d]   (K split over 4 groups)
__global__ __launch_bounds__(1024) void k_q(const float* __restrict__ Qp,
    const float* __restrict__ WQT, const float* __restrict__ WQ_b,
    float* __restrict__ Q)
{
  __shared__ float red[4][256];
  const int c = blockIdx.x, t = threadIdx.x;
  const int d = t & 255, kk = t >> 8;
  float acc = 0.f;
  #pragma unroll 4
  for (int k = kk * 64; k < kk * 64 + 64; ++k)
    acc += Qp[c * 256 + k] * WQT[k * 256 + d];
  red[kk][d] = acc;
  __syncthreads();
  if (kk == 0)
    Q[c * 256 + d] = red[0][d] + red[1][d] + red[2][d] + red[3][d] + WQ_b[d];
}

// QW = (Q@WK)/16 (fp64 acc), QO = Q@WO^T, qb = (Q@WK_b)/16 (K split over 4)
__global__ __launch_bounds__(1024) void k_fold(const float* __restrict__ Q,
    const float* __restrict__ WK_w, const float* __restrict__ WK_b,
    const float* __restrict__ WOT,
    float* __restrict__ QW, float* __restrict__ QO, float* __restrict__ qb)
{
  __shared__ float Qrow[256];
  __shared__ double redw[4][256];
  __shared__ float redo[4][256];
  const int c = blockIdx.x, t = threadIdx.x;
  const int d = t & 255, kk = t >> 8;
  if (t < 256) Qrow[t] = Q[c * 256 + t];
  __syncthreads();
  double aqw = 0.0;
  float aqo = 0.f;
  #pragma unroll 4
  for (int j = kk * 64; j < kk * 64 + 64; ++j) {
    float qcj = Qrow[j];
    aqw += (double)qcj * (double)WK_w[j * 256 + d];   // coalesced
    aqo += qcj * WOT[j * 256 + d];                    // coalesced
  }
  redw[kk][d] = aqw;
  redo[kk][d] = aqo;
  __syncthreads();
  if (kk == 0) {
    QW[c * 256 + d] = (float)((redw[0][d] + redw[1][d] + redw[2][d] + redw[3][d]) * 0.0625);
    QO[c * 256 + d] = redo[0][d] + redo[1][d] + redo[2][d] + redo[3][d];
  }
  __syncthreads();
  if (t < 256) redw[0][t] = (double)Qrow[t] * (double)WK_b[t];
  __syncthreads();
  for (int sft = 128; sft >= 1; sft >>= 1) {
    if (t < sft) redw[0][t] += redw[0][t + sft];
    __syncthreads();
  }
  if (t == 0) qb[c] = (float)(redw[0][0] * 0.0625);
}

// Wf[i][d] = sum_j WO_w[i][j]*WV_w[j][d]; bvo[i] = sum_j WV_b[j]*WO_w[i][j]
__global__ __launch_bounds__(1024) void k_wf(const float* __restrict__ WO_w,
    const float* __restrict__ WV_w, const float* __restrict__ WV_b,
    float* __restrict__ Wf, float* __restrict__ bvo)
{
  __shared__ float red[4][256];
  __shared__ float redb[4];
  const int i = blockIdx.x, t = threadIdx.x;
  const int d = t & 255, kk = t >> 8;
  float acc = 0.f;
  #pragma unroll 4
  for (int j = kk * 64; j < kk * 64 + 64; ++j)
    acc += WO_w[i * 256 + j] * WV_w[j * 256 + d];  // WO scalar, WV coalesced
  red[kk][d] = acc;
  if (d == 0) {
    float s = 0.f;
    for (int j = kk * 64; j < kk * 64 + 64; ++j) s += WV_b[j] * WO_w[i * 256 + j];
    redb[kk] = s;
  }
  __syncthreads();
  if (kk == 0) {
    Wf[i * 256 + d] = red[0][d] + red[1][d] + red[2][d] + red[3][d];
    if (d == 0) bvo[i] = redb[0] + redb[1] + redb[2] + redb[3];
  }
}

__global__ void k_starts(const int* __restrict__ batch, int* __restrict__ starts)
{
  int t = threadIdx.x;
  if (t > 64) return;
  if (t == 0) { starts[0] = 0; return; }
  if (t == 64) { starts[64] = N_NODES; return; }
  int lo = 0, hi = N_NODES;
  while (lo < hi) {
    int mid = (lo + hi) >> 1;
    if (batch[mid] < t) lo = mid + 1; else hi = mid;
  }
  starts[t] = lo;
}

// ---------------- fused: scores + softmax + argmax/mask + G (MFMA) ----------
// grid (NP, 64 graphs), 512 threads (8 waves), chunk = 32 nodes.
// Round-6 structure (195 us, passed) with ONE change: q is staged into LDS
// ONCE per kernel instead of re-gathered from global every chunk. Rationale:
// R3(8 waves/CU) == R6(16 waves/CU) == 195 us with no pipe saturated => a
// shared per-CU throughput wall; the unmodeled one is the L1/TA q-gather
// (64 gather instrs/thread/chunk, ~32 cache lines each ~ 110 us/CU). The
// previous session hit the same wall ("per-lane 64-line L1 gather").
// q LDS layout: qs[c*320 + k + 4*(k>>4)] -- the 4-float pad per 16 k makes
// the score-phase read (addr = c0*320 + h2*160 + kq*20 + kk*4) hit all 8
// bank-quads across kq (20*kq mod 32 = {0,20,8,28,16,4,24,12}) -> ~2-way.
// LDS total ~149 KB -> 1 block/CU (occupancy proven non-binding by R3==R6).
// Round-7's 16-address mapping REVERTED (b128 16-addr = unavoidable 4-way,
// +9M conflict cycles, 273 us).

__global__ __launch_bounds__(512, 1) void k_fused(
    const float* __restrict__ x, const int* __restrict__ starts,
    const float* __restrict__ qw, const float* __restrict__ qbv,
    float* __restrict__ Gp, float* __restrict__ asum,
    float* __restrict__ out_arg, float* __restrict__ out_msk)
{
  __shared__ float xs[32][256];                        // fp32 chunk, col-swizzled
  __shared__ float qs[64 * 320];                       // q fp32, k-padded rows
  __shared__ float ss[32][68];                         // scores [n][c]
  __shared__ float stats_m[32], stats_i[32];
  __shared__ __align__(16) unsigned short As[64][40];  // a bf16 [c][n]
  __shared__ __align__(16) unsigned short XsT[256][40];// x bf16 transposed [d][n]

  const int t = threadIdx.x;
  const int p = blockIdx.x, b = blockIdx.y;
  const int s0 = starts[b], s1 = starts[b + 1];
  const int w = t >> 6, lane = t & 63;
  const int wg = w & 3, wh = w >> 2;
  const int cp = lane >> 3, kq = lane & 7;
  const int c0 = wg * 16 + cp, c1 = c0 + 8;

  const float qb0 = qbv[c0], qb1 = qbv[c1];

  // ---- stage q into LDS once (coalesced read, k-padded scatter write)
  for (int i = t; i < 16384; i += 512) {
    const int c = i >> 8, k = i & 255;
    qs[c * 320 + k + 4 * (k >> 4)] = qw[i];
  }

  const float* qp0 = &qs[c0 * 320 + kq * 20];  // thread's q slice bases (LDS)
  const float* qp1 = &qs[c1 * 320 + kq * 20];

  f32x4 gacc[8];
  #pragma unroll
  for (int i = 0; i < 8; ++i) gacc[i] = (f32x4){0.f, 0.f, 0.f, 0.f};
  float asv0 = 0.f, asv1 = 0.f;

  const bool sel1 = (kq & 1), sel2 = (kq & 2), sel4 = (kq & 4);
  const int stcol = (lane * 4) ^ (4 * ((lane >> 3) & 7));  // staging store column
  const int dX = t & 255, hX = t >> 8;                     // XsT-fill mapping
  const int dsz = dX ^ (4 * ((dX >> 5) & 7));              // swizzled read column

  __syncthreads();   // qs ready

  #pragma unroll 1
  for (int base = s0 + p * 32; base < s1; base += NP * 32) {
    // ---- stage x chunk: wave w covers rows 4w..4w+3 (coalesced 1KB/row)
    #pragma unroll
    for (int i = 0; i < 4; ++i) {
      int r = w * 4 + i;
      int gr = base + r; if (gr >= s1) gr = s1 - 1;
      float4 v = *(const float4*)&x[(size_t)gr * 256 + lane * 4];
      *(float4*)&xs[r][stcol] = v;
    }
    __syncthreads();
    // ---- XsT fill: 2 threads/column; thread packs rows hX*16..hX*16+15
    #pragma unroll
    for (int g = 0; g < 4; ++g) {
      const int r0 = hX * 16 + g * 4;
      ushort4 pk;
      pk.x = f2bf(xs[r0 + 0][dsz]);
      pk.y = f2bf(xs[r0 + 1][dsz]);
      pk.z = f2bf(xs[r0 + 2][dsz]);
      pk.w = f2bf(xs[r0 + 3][dsz]);
      *(ushort4*)&XsT[dX][r0] = pk;
    }
    // ---- scores: wave-half wh covers nodes wh*16..wh*16+15, 4 sub-blocks of 4
    #pragma unroll 1
    for (int nb = 0; nb < 4; ++nb) {
      float a0[4], a1[4];
      #pragma unroll
      for (int n = 0; n < 4; ++n) { a0[n] = 0.f; a1[n] = 0.f; }
      const float* xb = &xs[wh * 16 + nb * 4][0];
      #pragma unroll 1
      for (int h2 = 0; h2 < 2; ++h2) {
        const float* q0b = qp0 + h2 * 160;
        const float* q1b = qp1 + h2 * 160;
        // k4 = 0,1
        {
          float4 qa0 = *(const float4*)&q0b[0];
          float4 qa1 = *(const float4*)&q0b[4];
          float4 qc0 = *(const float4*)&q1b[0];
          float4 qc1 = *(const float4*)&q1b[4];
          #pragma unroll
          for (int k4 = 0; k4 < 2; ++k4) {
            const int colb = h2 * 128 + kq * 16 + k4 * 4;
            const int col = colb ^ (4 * ((colb >> 5) & 7));
            const float4 qa = k4 ? qa1 : qa0;
            const float4 qc = k4 ? qc1 : qc0;
            #pragma unroll
            for (int n = 0; n < 4; ++n) {
              float4 xv = *(const float4*)&xb[n * 256 + col];
              a0[n] = fmaf(qa.w, xv.w, fmaf(qa.z, xv.z, fmaf(qa.y, xv.y, fmaf(qa.x, xv.x, a0[n]))));
              a1[n] = fmaf(qc.w, xv.w, fmaf(qc.z, xv.z, fmaf(qc.y, xv.y, fmaf(qc.x, xv.x, a1[n]))));
            }
          }
        }
        // k4 = 2,3
        {
          float4 qa2 = *(const float4*)&q0b[8];
          float4 qa3 = *(const float4*)&q0b[12];
          float4 qc2 = *(const float4*)&q1b[8];
          float4 qc3 = *(const float4*)&q1b[12];
          #pragma unroll
          for (int k4 = 2; k4 < 4; ++k4) {
            const int colb = h2 * 128 + kq * 16 + k4 * 4;
            const int col = colb ^ (4 * ((colb >> 5) & 7));
            const float4 qa = (k4 == 2) ? qa2 : qa3;
            const float4 qc = (k4 == 2) ? qc2 : qc3;
            #pragma unroll
            for (int n = 0; n < 4; ++n) {
              float4 xv = *(const float4*)&xb[n * 256 + col];
              a0[n] = fmaf(qa.w, xv.w, fmaf(qa.z, xv.z, fmaf(qa.y, xv.y, fmaf(qa.x, xv.x, a0[n]))));
              a1[n] = fmaf(qc.w, xv.w, fmaf(qc.z, xv.z, fmaf(qc.y, xv.y, fmaf(qc.x, xv.x, a1[n]))));
            }
          }
        }
      }
      // staged reduce over kq: xor1 resolves n bit0, xor2 n bit1, xor4 cluster.
      // Lane kq ends with (c = kq&4 ? c1 : c0, node = wh*16 + nb*4 + (kq&3)).
      {
        float r00 = mrg1(a0[0], a0[1], sel1);
        float r01 = mrg1(a0[2], a0[3], sel1);
        float r10 = mrg1(a1[0], a1[1], sel1);
        float r11 = mrg1(a1[2], a1[3], sel1);
        float t0  = mrg2(r00, r01, sel2);
        float t1  = mrg2(r10, r11, sel2);
        float val = mrg4(t0, t1, sel4);
        const int nn = wh * 16 + nb * 4 + (kq & 3);   // wh*16 included
        ss[nn][sel4 ? c1 : c0] = val + (sel4 ? qb1 : qb0);
      }
    }
    __syncthreads();
    // ---- softmax stats + argmax: threads 0..255, 8 threads/node
    if (t < 256) {
      const int nn = t >> 3, oct = t & 7;
      float v8[8];
      #pragma unroll
      for (int u = 0; u < 8; ++u) v8[u] = ss[nn][oct * 8 + u];
      float m = v8[0]; int am = oct * 8;
      #pragma unroll
      for (int u = 1; u < 8; ++u)
        if (v8[u] > m) { m = v8[u]; am = oct * 8 + u; }   // strict >: first max
      #pragma unroll
      for (int d = 1; d < 8; d <<= 1) {
        float mo = __shfl_xor(m, d);
        int ao = __shfl_xor(am, d);
        if (mo > m || (mo == m && ao < am)) { m = mo; am = ao; }
      }
      float s = 0.f;
      #pragma unroll
      for (int u = 0; u < 8; ++u) s += __expf(v8[u] - m);
      #pragma unroll
      for (int d = 1; d < 8; d <<= 1) s += __shfl_xor(s, d);
      if (oct == 0) {
        stats_m[nn] = m;
        stats_i[nn] = 1.f / s;
        int n = base + nn;
        if (n < s1) {
          int pos = n - s0;
          out_arg[(size_t)b * MAXL + pos] = (float)am;
          out_msk[(size_t)b * MAXL + pos] = 1.0f;
        }
      }
    }
    __syncthreads();
    // ---- a-values -> As (bf16) + asum; thread covers n = 4kq+2wh+{0,1}
    {
      unsigned short pb0[2], pb1[2];
      #pragma unroll
      for (int i = 0; i < 2; ++i) {
        int nn = 4 * kq + 2 * wh + i;
        bool valid = (base + nn) < s1;
        float m = stats_m[nn], inv = stats_i[nn];
        float av0 = valid ? __expf(ss[nn][c0] - m) * inv : 0.f;
        float av1 = valid ? __expf(ss[nn][c1] - m) * inv : 0.f;
        asv0 += av0; asv1 += av1;
        pb0[i] = f2bf(av0);
        pb1[i] = f2bf(av1);
      }
      *(ushort2*)&As[c0][4 * kq + 2 * wh] = *(const ushort2*)pb0;
      *(ushort2*)&As[c1][4 * kq + 2 * wh] = *(const ushort2*)pb1;
    }
    __syncthreads();
    // ---- G MFMA: wave handles clusters 16wg..16wg+15, dt half wh*8..wh*8+7
    {
      const int q = lane >> 4, mm = lane & 15;
      bf16x8 afrag = *(const bf16x8*)&As[16 * wg + mm][q * 8];
      #pragma unroll
      for (int dt2 = 0; dt2 < 8; ++dt2) {
        const int dt = wh * 8 + dt2;
        bf16x8 bfrag = *(const bf16x8*)&XsT[16 * dt + mm][q * 8];
        gacc[dt2] = __builtin_amdgcn_mfma_f32_16x16x32_bf16(afrag, bfrag, gacc[dt2], 0, 0, 0);
      }
    }
    __syncthreads();
  }

  // ---- epilogue: store G slab (D layout: row=4*(lane>>4)+r, col=lane&15)
  {
    float* g = Gp + ((size_t)p * 64 + b) * 16384;
    const int q = lane >> 4, mm = lane & 15;
    #pragma unroll
    for (int dt2 = 0; dt2 < 8; ++dt2) {
      const int dt = wh * 8 + dt2;
      #pragma unroll
      for (int r = 0; r < 4; ++r)
        g[(size_t)(16 * wg + q * 4 + r) * 256 + 16 * dt + mm] = gacc[dt2][r];
    }
  }
  // asum: reduce per-thread partials over kq, one atomic per cluster per wh
  asv0 = kq_sum(asv0);
  asv1 = kq_sum(asv1);
  if (kq == 0) {
    atomicAdd(&asum[b * 64 + c0], asv0);
    atomicAdd(&asum[b * 64 + c1], asv1);
  }
}

// ---------------- finalize: out = relu(qo + (sum_p Gp)@Wf^T + asum*bvo + b) --

__global__ __launch_bounds__(256) void k_final(const float* __restrict__ Gp,
    int npart, const float* __restrict__ Wf, const float* __restrict__ qo,
    const float* __restrict__ asum, const float* __restrict__ bvo,
    const float* __restrict__ WO_b, float* __restrict__ out)
{
  __shared__ float gs[64 * 68];
  __shared__ float wfs[64 * 68];
  const int t = threadIdx.x;
  const int b = blockIdx.x >> 2;
  const int is = (blockIdx.x & 3) * 64;
  const int tx = t & 15, ty = t >> 4;
  const int sr = t >> 4, sq = t & 15;

  float acc[4][4];
  #pragma unroll
  for (int j = 0; j < 4; ++j)
    #pragma unroll
    for (int u = 0; u < 4; ++u) acc[j][u] = 0.f;

  for (int kc = 0; kc < 4; ++kc) {
    const int k0 = kc * 64;
    #pragma unroll
    for (int u = 0; u < 4; ++u) {
      int row = sr + 16 * u;
      float4 g = make_float4(0.f, 0.f, 0.f, 0.f);
      for (int p = 0; p < npart; ++p) {
        float4 gv = *(const float4*)&Gp[((size_t)p * 64 + b) * 16384
                                        + row * 256 + k0 + sq * 4];
        g.x += gv.x; g.y += gv.y; g.z += gv.z; g.w += gv.w;
      }
      *(float4*)&gs[row * 68 + sq * 4] = g;
      *(float4*)&wfs[row * 68 + sq * 4] =
          *(const float4*)&Wf[(size_t)(is + row) * 256 + k0 + sq * 4];
    }
    __syncthreads();
    #pragma unroll
    for (int k4 = 0; k4 < 16; ++k4) {
      float4 gr[4], wr[4];
      #pragma unroll
      for (int j = 0; j < 4; ++j) gr[j] = *(const float4*)&gs[(ty + 16 * j) * 68 + k4 * 4];
      #pragma unroll
      for (int u = 0; u < 4; ++u) wr[u] = *(const float4*)&wfs[(tx + 16 * u) * 68 + k4 * 4];
      #pragma unroll
      for (int j = 0; j < 4; ++j)
        #pragma unroll
        for (int u = 0; u < 4; ++u)
          acc[j][u] += gr[j].x * wr[u].x + gr[j].y * wr[u].y
                     + gr[j].z * wr[u].z + gr[j].w * wr[u].w;
    }
    __syncthreads();
  }

  #pragma unroll
  for (int j = 0; j < 4; ++j)
    #pragma unroll
    for (int u = 0; u < 4; ++u) {
      int cc = ty + 16 * j, i = is + tx + 16 * u;
      float v = acc[j][u] + qo[cc * 256 + i] + asum[b * 64 + cc] * bvo[i] + WO_b[i];
      out[(size_t)b * 16384 + cc * 256 + i] = fmaxf(v, 0.f);
    }
}

// ---------------- launch ----------------

extern "C" void kernel_launch(void* const* d_in, const int* in_sizes, int n_in,
                              void* d_out, int out_size, void* d_ws, size_t ws_size,
                              hipStream_t stream) {
  const float* x    = (const float*)d_in[0];
  const int*   batch= (const int*)d_in[1];
  const float* Qp   = (const float*)d_in[2];
  const float* WQ_w = (const float*)d_in[3];
  const float* WQ_b = (const float*)d_in[4];
  const float* WK_w = (const float*)d_in[5];
  const float* WK_b = (const float*)d_in[6];
  const float* WV_w = (const float*)d_in[7];
  const float* WV_b = (const float*)d_in[8];
  const float* WO_w = (const float*)d_in[9];
  const float* WO_b = (const float*)d_in[10];

  float* ws   = (float*)d_ws;
  float* QW   = ws + OFF_QW;
  float* QO   = ws + OFF_QO;
  float* Wf   = ws + OFF_WF;
  float* qb   = ws + OFF_QB;
  float* bvo  = ws + OFF_BVO;
  int*   starts = (int*)(ws + OFF_STARTS);
  float* asum = ws + OFF_ASUM;
  float* Q    = ws + OFF_Q;
  float* WQT  = ws + OFF_WQT;
  float* WOT  = ws + OFF_WOT;
  float* Gp   = ws + OFF_GP;

  float* out     = (float*)d_out;                 // [64][64][256]
  float* out_arg = out + 64 * 64 * 256;           // [64][4096]
  float* out_msk = out_arg + 64 * MAXL;           // [64][4096]

  hipMemsetAsync(asum, 0, 64 * 64 * sizeof(float), stream);
  hipMemsetAsync(out_arg, 0, (size_t)2 * 64 * MAXL * sizeof(float), stream);

  k_tr<<<dim3(8, 8, 2), 256, 0, stream>>>(WQ_w, WO_w, WQT, WOT);
  k_wf<<<256, 1024, 0, stream>>>(WO_w, WV_w, WV_b, Wf, bvo);
  k_starts<<<1, 128, 0, stream>>>(batch, starts);
  k_q<<<64, 1024, 0, stream>>>(Qp, WQT, WQ_b, Q);
  k_fold<<<64, 1024, 0, stream>>>(Q, WK_w, WK_b, WOT, QW, QO, qb);

  k_fused<<<dim3(NP, 64), 512, 0, stream>>>(x, starts, QW, qb, Gp, asum,
                                            out_arg, out_msk);
  k_final<<<64 * 4, 256, 0, stream>>>(Gp, NP, Wf, QO, asum, bvo, WO_b, out);
}

// Round 9
// 382.948 us; speedup vs baseline: 1.3058x; 1.0979x over previous
//
#include <hip/hip_runtime.h>

#define N_NODES 131072
#define MAXL 4096
#define NP 8

typedef __attribute__((ext_vector_type(8))) short bf16x8;
typedef __attribute__((ext_vector_type(4))) float f32x4;

// ws float offsets
#define OFF_QW     0u          // 64*256   folded (Q@WK)/16
#define OFF_QO     16384u      // 64*256   Q@WO^T
#define OFF_WF     32768u      // 256*256  WO@WV
#define OFF_QB     98304u      // 64
#define OFF_BVO    98368u      // 256
#define OFF_STARTS 98624u      // 65 ints (padded)
#define OFF_ASUM   98752u      // 64*64
#define OFF_Q      102848u     // 64*256  (unused now)
#define OFF_WQT    119232u     // 256*256
#define OFF_WOT    184768u     // 256*256
#define OFF_GP     250304u     // 8 * 64 * 16384  (end = 8638912 floats = 34.6 MB)

__device__ __forceinline__ unsigned short f2bf(float f) {
  union { float f; unsigned int u; } v; v.f = f;
  unsigned int u = v.u + 0x7FFFu + ((v.u >> 16) & 1u);  // RNE
  return (unsigned short)(u >> 16);
}

// DPP / swizzle lane-moves (value from lane^1 / lane^2 / lane^4)
__device__ __forceinline__ float dppx1(float v) {
  return __int_as_float(__builtin_amdgcn_update_dpp(0, __float_as_int(v), 0xB1, 0xF, 0xF, true));
}
__device__ __forceinline__ float dppx2(float v) {
  return __int_as_float(__builtin_amdgcn_update_dpp(0, __float_as_int(v), 0x4E, 0xF, 0xF, true));
}
__device__ __forceinline__ float swzx4(float v) {
  return __int_as_float(__builtin_amdgcn_ds_swizzle(__float_as_int(v), 0x101F));
}
// full butterfly sum over 8 lanes (used for asum only)
__device__ __forceinline__ float kq_sum(float v) {
  v += dppx1(v); v += dppx2(v); v += swzx4(v); return v;
}
// staged merge: keep own value (by sel), add partner's copy of the other
__device__ __forceinline__ float mrg1(float u, float v, bool sel) {
  float snd = sel ? u : v, kp = sel ? v : u; return kp + dppx1(snd);
}
__device__ __forceinline__ float mrg2(float u, float v, bool sel) {
  float snd = sel ? u : v, kp = sel ? v : u; return kp + dppx2(snd);
}
__device__ __forceinline__ float mrg4(float u, float v, bool sel) {
  float snd = sel ? u : v, kp = sel ? v : u; return kp + swzx4(snd);
}

// ---------------- setup ----------------

// transpose WQ_w (z=0) and WO_w (z=1) into WQT / WOT
__global__ __launch_bounds__(256) void k_tr(const float* __restrict__ WQ_w,
    const float* __restrict__ WO_w, float* __restrict__ WQT, float* __restrict__ WOT)
{
  __shared__ float tile[32][33];
  const float* src = blockIdx.z ? WO_w : WQ_w;
  float* dst = blockIdx.z ? WOT : WQT;
  const int bx = blockIdx.x * 32, by = blockIdx.y * 32;
  const int tx = threadIdx.x & 31, ty = threadIdx.x >> 5;
  #pragma unroll
  for (int i = 0; i < 4; ++i)
    tile[ty + 8 * i][tx] = src[(size_t)(by + ty + 8 * i) * 256 + bx + tx];
  __syncthreads();
  #pragma unroll
  for (int i = 0; i < 4; ++i)
    dst[(size_t)(bx + ty + 8 * i) * 256 + by + tx] = tile[tx][ty + 8 * i];
}

// k_prep: fused {k_fold(+k_q) | k_wf | k_starts} by block role.
// blocks 0..63: fold (c = bid), 64..319: wf (i = bid-64), 320: starts.
__global__ __launch_bounds__(1024) void k_prep(
    const float* __restrict__ Qp, const float* __restrict__ WQT,
    const float* __restrict__ WQ_b,
    const float* __restrict__ WK_w, const float* __restrict__ WK_b,
    const float* __restrict__ WOT,
    const float* __restrict__ WO_w, const float* __restrict__ WV_w,
    const float* __restrict__ WV_b,
    const int* __restrict__ batch,
    float* __restrict__ QW, float* __restrict__ QO, float* __restrict__ qb,
    float* __restrict__ Wf, float* __restrict__ bvo, int* __restrict__ starts)
{
  const int bid = blockIdx.x, t = threadIdx.x;
  const int d = t & 255, kk = t >> 8;

  if (bid < 64) {
    // ---- fold role: Qrow = Qp[c]@WQT + b, then QW/QO/qb
    __shared__ float Qrow[256];
    __shared__ double redw[4][256];
    __shared__ float redo[4][256];
    const int c = bid;
    // Qrow via K-split (coalesced in d)
    {
      float acc = 0.f;
      #pragma unroll 4
      for (int k = kk * 64; k < kk * 64 + 64; ++k)
        acc += Qp[c * 256 + k] * WQT[k * 256 + d];
      redo[kk][d] = acc;
    }
    __syncthreads();
    if (kk == 0)
      Qrow[d] = redo[0][d] + redo[1][d] + redo[2][d] + redo[3][d] + WQ_b[d];
    __syncthreads();
    double aqw = 0.0;
    float aqo = 0.f;
    #pragma unroll 4
    for (int j = kk * 64; j < kk * 64 + 64; ++j) {
      float qcj = Qrow[j];
      aqw += (double)qcj * (double)WK_w[j * 256 + d];   // coalesced
      aqo += qcj * WOT[j * 256 + d];                    // coalesced
    }
    redw[kk][d] = aqw;
    redo[kk][d] = aqo;
    __syncthreads();
    if (kk == 0) {
      QW[c * 256 + d] = (float)((redw[0][d] + redw[1][d] + redw[2][d] + redw[3][d]) * 0.0625);
      QO[c * 256 + d] = redo[0][d] + redo[1][d] + redo[2][d] + redo[3][d];
    }
    __syncthreads();
    if (t < 256) redw[0][t] = (double)Qrow[t] * (double)WK_b[t];
    __syncthreads();
    for (int sft = 128; sft >= 1; sft >>= 1) {
      if (t < sft) redw[0][t] += redw[0][t + sft];
      __syncthreads();
    }
    if (t == 0) qb[c] = (float)(redw[0][0] * 0.0625);
  } else if (bid < 320) {
    // ---- wf role
    __shared__ float red[4][256];
    __shared__ float redb[4];
    const int i = bid - 64;
    float acc = 0.f;
    #pragma unroll 4
    for (int j = kk * 64; j < kk * 64 + 64; ++j)
      acc += WO_w[i * 256 + j] * WV_w[j * 256 + d];  // WO scalar, WV coalesced
    red[kk][d] = acc;
    if (d == 0) {
      float s = 0.f;
      for (int j = kk * 64; j < kk * 64 + 64; ++j) s += WV_b[j] * WO_w[i * 256 + j];
      redb[kk] = s;
    }
    __syncthreads();
    if (kk == 0) {
      Wf[i * 256 + d] = red[0][d] + red[1][d] + red[2][d] + red[3][d];
      if (d == 0) bvo[i] = redb[0] + redb[1] + redb[2] + redb[3];
    }
  } else {
    // ---- starts role
    if (t > 64) return;
    if (t == 0) { starts[0] = 0; return; }
    if (t == 64) { starts[64] = N_NODES; return; }
    int lo = 0, hi = N_NODES;
    while (lo < hi) {
      int mid = (lo + hi) >> 1;
      if (batch[mid] < t) lo = mid + 1; else hi = mid;
    }
    starts[t] = lo;
  }
}

// ---------------- fused: scores + softmax + argmax/mask + G (MFMA) ----------
// grid (NP, 64 graphs), 512 threads (8 waves), chunk = 32 nodes.
// At 1 block/CU (2 waves/SIMD) the per-wave VGPR budget is 256, so q lives
// in 128 PERSISTENT registers (32 float4, loaded once from global) -- zero
// q-LDS traffic (R8's q-LDS layout was multi-way conflicted: c*320 === 0
// mod 32, conflicts 2.6M -> 11.35M). Score remap: wave = (wgS = w&1: 32
// clusters, whS = w>>1: 8 nodes); thread owns 4 clusters (cp+8j, j=0..3),
// k-slice kq*16 per 128-half. Each xs b128 read feeds 16 FMAs; score LDS
// reads drop 192 -> 64 per thread per chunk. xs address pattern per instr
// identical to round 6 (8 distinct addrs, swizzled, conflict-free).
// Reduce: same bit-exact butterfly (xor1->n0, xor2->n1, xor4->j0); lane
// ends with clusters j=(kq>>2)&1 and j+2. Stats/a-phase/MFMA/epilogue keep
// round-6 mappings verbatim (wg = w&3, wh = w>>2).

__global__ __launch_bounds__(512, 2) void k_fused(
    const float* __restrict__ x, const int* __restrict__ starts,
    const float* __restrict__ qw, const float* __restrict__ qbv,
    float* __restrict__ Gp, float* __restrict__ asum,
    float* __restrict__ out_arg, float* __restrict__ out_msk)
{
  __shared__ float xs[32][256];                        // fp32 chunk, col-swizzled
  __shared__ float ss[32][68];                         // scores [n][c]
  __shared__ float stats_m[32], stats_i[32];
  __shared__ __align__(16) unsigned short As[64][40];  // a bf16 [c][n]
  __shared__ __align__(16) unsigned short XsT[256][40];// x bf16 transposed [d][n]

  const int t = threadIdx.x;
  const int p = blockIdx.x, b = blockIdx.y;
  const int s0 = starts[b], s1 = starts[b + 1];
  const int w = t >> 6, lane = t & 63;
  const int wg = w & 3, wh = w >> 2;                   // a-phase / MFMA mapping
  const int cp = lane >> 3, kq = lane & 7;
  const int c0 = wg * 16 + cp, c1 = c0 + 8;
  const float qb0 = qbv[c0], qb1 = qbv[c1];

  // score-phase mapping
  const int wgS = w & 1, whS = w >> 1;
  const bool sel1 = (kq & 1), sel2 = (kq & 2), sel4 = (kq & 4);
  const int cBase = wgS * 32 + cp;                     // j=0 cluster
  const int czA = cBase + (sel4 ? 8 : 0);              // z0's cluster
  const int czB = czA + 16;                            // z1's cluster
  const float qbzA = qbv[czA], qbzB = qbv[czB];

  // ---- q into registers: 32 float4 = 128 VGPRs, loaded ONCE from global
  float4 qr[4][2][4];                                  // [j][h2][k4]
  #pragma unroll
  for (int j = 0; j < 4; ++j) {
    const float* qgj = qw + (size_t)(cBase + 8 * j) * 256 + kq * 16;
    #pragma unroll
    for (int h2 = 0; h2 < 2; ++h2)
      #pragma unroll
      for (int k4 = 0; k4 < 4; ++k4)
        qr[j][h2][k4] = *(const float4*)&qgj[h2 * 128 + k4 * 4];
  }

  f32x4 gacc[8];
  #pragma unroll
  for (int i = 0; i < 8; ++i) gacc[i] = (f32x4){0.f, 0.f, 0.f, 0.f};
  float asv0 = 0.f, asv1 = 0.f;

  const int stcol = (lane * 4) ^ (4 * ((lane >> 3) & 7));  // staging store column
  const int dX = t & 255, hX = t >> 8;                     // XsT-fill mapping
  const int dsz = dX ^ (4 * ((dX >> 5) & 7));              // swizzled read column

  #pragma unroll 1
  for (int base = s0 + p * 32; base < s1; base += NP * 32) {
    // ---- stage x chunk: wave w covers rows 4w..4w+3 (coalesced 1KB/row)
    #pragma unroll
    for (int i = 0; i < 4; ++i) {
      int r = w * 4 + i;
      int gr = base + r; if (gr >= s1) gr = s1 - 1;
      float4 v = *(const float4*)&x[(size_t)gr * 256 + lane * 4];
      *(float4*)&xs[r][stcol] = v;
    }
    __syncthreads();
    // ---- XsT fill: 2 threads/column; thread packs rows hX*16..hX*16+15
    #pragma unroll
    for (int g = 0; g < 4; ++g) {
      const int r0 = hX * 16 + g * 4;
      ushort4 pk;
      pk.x = f2bf(xs[r0 + 0][dsz]);
      pk.y = f2bf(xs[r0 + 1][dsz]);
      pk.z = f2bf(xs[r0 + 2][dsz]);
      pk.w = f2bf(xs[r0 + 3][dsz]);
      *(ushort4*)&XsT[dX][r0] = pk;
    }
    // ---- scores: wave covers nodes whS*8..whS*8+7, 2 sub-blocks of 4
    #pragma unroll 1
    for (int nb = 0; nb < 2; ++nb) {
      float acc[4][4];                                  // [j][n]
      #pragma unroll
      for (int j = 0; j < 4; ++j)
        #pragma unroll
        for (int n = 0; n < 4; ++n) acc[j][n] = 0.f;
      const float* xb = &xs[whS * 8 + nb * 4][0];
      #pragma unroll
      for (int h2 = 0; h2 < 2; ++h2) {
        #pragma unroll
        for (int k4 = 0; k4 < 4; ++k4) {
          const int colb = h2 * 128 + kq * 16 + k4 * 4;
          const int col = colb ^ (4 * ((colb >> 5) & 7));
          const float4 q0 = qr[0][h2][k4];
          const float4 q1 = qr[1][h2][k4];
          const float4 q2 = qr[2][h2][k4];
          const float4 q3 = qr[3][h2][k4];
          #pragma unroll
          for (int n = 0; n < 4; ++n) {
            float4 xv = *(const float4*)&xb[n * 256 + col];
            acc[0][n] = fmaf(q0.w, xv.w, fmaf(q0.z, xv.z, fmaf(q0.y, xv.y, fmaf(q0.x, xv.x, acc[0][n]))));
            acc[1][n] = fmaf(q1.w, xv.w, fmaf(q1.z, xv.z, fmaf(q1.y, xv.y, fmaf(q1.x, xv.x, acc[1][n]))));
            acc[2][n] = fmaf(q2.w, xv.w, fmaf(q2.z, xv.z, fmaf(q2.y, xv.y, fmaf(q2.x, xv.x, acc[2][n]))));
            acc[3][n] = fmaf(q3.w, xv.w, fmaf(q3.z, xv.z, fmaf(q3.y, xv.y, fmaf(q3.x, xv.x, acc[3][n]))));
          }
        }
      }
      // staged reduce: xor1->n bit0, xor2->n bit1, xor4->j bit0.
      // Lane ends with n = kq&3 and clusters j = (sel4?1:0) and j+2.
      {
        float r0 = mrg1(acc[0][0], acc[0][1], sel1);
        float r1 = mrg1(acc[0][2], acc[0][3], sel1);
        float r2 = mrg1(acc[1][0], acc[1][1], sel1);
        float r3 = mrg1(acc[1][2], acc[1][3], sel1);
        float r4 = mrg1(acc[2][0], acc[2][1], sel1);
        float r5 = mrg1(acc[2][2], acc[2][3], sel1);
        float r6 = mrg1(acc[3][0], acc[3][1], sel1);
        float r7 = mrg1(acc[3][2], acc[3][3], sel1);
        float w0 = mrg2(r0, r1, sel2);
        float w1 = mrg2(r2, r3, sel2);
        float w2 = mrg2(r4, r5, sel2);
        float w3 = mrg2(r6, r7, sel2);
        float z0 = mrg4(w0, w1, sel4);
        float z1 = mrg4(w2, w3, sel4);
        const int nn = whS * 8 + nb * 4 + (kq & 3);
        ss[nn][czA] = z0 + qbzA;
        ss[nn][czB] = z1 + qbzB;
      }
    }
    __syncthreads();
    // ---- softmax stats + argmax: threads 0..255, 8 threads/node
    if (t < 256) {
      const int nn = t >> 3, oct = t & 7;
      float v8[8];
      #pragma unroll
      for (int u = 0; u < 8; ++u) v8[u] = ss[nn][oct * 8 + u];
      float m = v8[0]; int am = oct * 8;
      #pragma unroll
      for (int u = 1; u < 8; ++u)
        if (v8[u] > m) { m = v8[u]; am = oct * 8 + u; }   // strict >: first max
      #pragma unroll
      for (int d = 1; d < 8; d <<= 1) {
        float mo = __shfl_xor(m, d);
        int ao = __shfl_xor(am, d);
        if (mo > m || (mo == m && ao < am)) { m = mo; am = ao; }
      }
      float s = 0.f;
      #pragma unroll
      for (int u = 0; u < 8; ++u) s += __expf(v8[u] - m);
      #pragma unroll
      for (int d = 1; d < 8; d <<= 1) s += __shfl_xor(s, d);
      if (oct == 0) {
        stats_m[nn] = m;
        stats_i[nn] = 1.f / s;
        int n = base + nn;
        if (n < s1) {
          int pos = n - s0;
          out_arg[(size_t)b * MAXL + pos] = (float)am;
          out_msk[(size_t)b * MAXL + pos] = 1.0f;
        }
      }
    }
    __syncthreads();
    // ---- a-values -> As (bf16) + asum; thread covers n = 4kq+2wh+{0,1}
    {
      unsigned short pb0[2], pb1[2];
      #pragma unroll
      for (int i = 0; i < 2; ++i) {
        int nn = 4 * kq + 2 * wh + i;
        bool valid = (base + nn) < s1;
        float m = stats_m[nn], inv = stats_i[nn];
        float av0 = valid ? __expf(ss[nn][c0] - m) * inv : 0.f;
        float av1 = valid ? __expf(ss[nn][c1] - m) * inv : 0.f;
        asv0 += av0; asv1 += av1;
        pb0[i] = f2bf(av0);
        pb1[i] = f2bf(av1);
      }
      *(ushort2*)&As[c0][4 * kq + 2 * wh] = *(const ushort2*)pb0;
      *(ushort2*)&As[c1][4 * kq + 2 * wh] = *(const ushort2*)pb1;
    }
    __syncthreads();
    // ---- G MFMA: wave handles clusters 16wg..16wg+15, dt half wh*8..wh*8+7
    {
      const int q = lane >> 4, mm = lane & 15;
      bf16x8 afrag = *(const bf16x8*)&As[16 * wg + mm][q * 8];
      #pragma unroll
      for (int dt2 = 0; dt2 < 8; ++dt2) {
        const int dt = wh * 8 + dt2;
        bf16x8 bfrag = *(const bf16x8*)&XsT[16 * dt + mm][q * 8];
        gacc[dt2] = __builtin_amdgcn_mfma_f32_16x16x32_bf16(afrag, bfrag, gacc[dt2], 0, 0, 0);
      }
    }
    __syncthreads();
  }

  // ---- epilogue: store G slab (D layout: row=4*(lane>>4)+r, col=lane&15)
  {
    float* g = Gp + ((size_t)p * 64 + b) * 16384;
    const int q = lane >> 4, mm = lane & 15;
    #pragma unroll
    for (int dt2 = 0; dt2 < 8; ++dt2) {
      const int dt = wh * 8 + dt2;
      #pragma unroll
      for (int r = 0; r < 4; ++r)
        g[(size_t)(16 * wg + q * 4 + r) * 256 + 16 * dt + mm] = gacc[dt2][r];
    }
  }
  // asum: reduce per-thread partials over kq, one atomic per cluster per wh
  asv0 = kq_sum(asv0);
  asv1 = kq_sum(asv1);
  if (kq == 0) {
    atomicAdd(&asum[b * 64 + c0], asv0);
    atomicAdd(&asum[b * 64 + c1], asv1);
  }
}

// ---------------- finalize: out = relu(qo + (sum_p Gp)@Wf^T + asum*bvo + b) --

__global__ __launch_bounds__(256) void k_final(const float* __restrict__ Gp,
    int npart, const float* __restrict__ Wf, const float* __restrict__ qo,
    const float* __restrict__ asum, const float* __restrict__ bvo,
    const float* __restrict__ WO_b, float* __restrict__ out)
{
  __shared__ float gs[64 * 68];
  __shared__ float wfs[64 * 68];
  const int t = threadIdx.x;
  const int b = blockIdx.x >> 2;
  const int is = (blockIdx.x & 3) * 64;
  const int tx = t & 15, ty = t >> 4;
  const int sr = t >> 4, sq = t & 15;

  float acc[4][4];
  #pragma unroll
  for (int j = 0; j < 4; ++j)
    #pragma unroll
    for (int u = 0; u < 4; ++u) acc[j][u] = 0.f;

  for (int kc = 0; kc < 4; ++kc) {
    const int k0 = kc * 64;
    #pragma unroll
    for (int u = 0; u < 4; ++u) {
      int row = sr + 16 * u;
      float4 g = make_float4(0.f, 0.f, 0.f, 0.f);
      for (int p = 0; p < npart; ++p) {
        float4 gv = *(const float4*)&Gp[((size_t)p * 64 + b) * 16384
                                        + row * 256 + k0 + sq * 4];
        g.x += gv.x; g.y += gv.y; g.z += gv.z; g.w += gv.w;
      }
      *(float4*)&gs[row * 68 + sq * 4] = g;
      *(float4*)&wfs[row * 68 + sq * 4] =
          *(const float4*)&Wf[(size_t)(is + row) * 256 + k0 + sq * 4];
    }
    __syncthreads();
    #pragma unroll
    for (int k4 = 0; k4 < 16; ++k4) {
      float4 gr[4], wr[4];
      #pragma unroll
      for (int j = 0; j < 4; ++j) gr[j] = *(const float4*)&gs[(ty + 16 * j) * 68 + k4 * 4];
      #pragma unroll
      for (int u = 0; u < 4; ++u) wr[u] = *(const float4*)&wfs[(tx + 16 * u) * 68 + k4 * 4];
      #pragma unroll
      for (int j = 0; j < 4; ++j)
        #pragma unroll
        for (int u = 0; u < 4; ++u)
          acc[j][u] += gr[j].x * wr[u].x + gr[j].y * wr[u].y
                     + gr[j].z * wr[u].z + gr[j].w * wr[u].w;
    }
    __syncthreads();
  }

  #pragma unroll
  for (int j = 0; j < 4; ++j)
    #pragma unroll
    for (int u = 0; u < 4; ++u) {
      int cc = ty + 16 * j, i = is + tx + 16 * u;
      float v = acc[j][u] + qo[cc * 256 + i] + asum[b * 64 + cc] * bvo[i] + WO_b[i];
      out[(size_t)b * 16384 + cc * 256 + i] = fmaxf(v, 0.f);
    }
}

// ---------------- launch ----------------

extern "C" void kernel_launch(void* const* d_in, const int* in_sizes, int n_in,
                              void* d_out, int out_size, void* d_ws, size_t ws_size,
                              hipStream_t stream) {
  const float* x    = (const float*)d_in[0];
  const int*   batch= (const int*)d_in[1];
  const float* Qp   = (const float*)d_in[2];
  const float* WQ_w = (const float*)d_in[3];
  const float* WQ_b = (const float*)d_in[4];
  const float* WK_w = (const float*)d_in[5];
  const float* WK_b = (const float*)d_in[6];
  const float* WV_w = (const float*)d_in[7];
  const float* WV_b = (const float*)d_in[8];
  const float* WO_w = (const float*)d_in[9];
  const float* WO_b = (const float*)d_in[10];

  float* ws   = (float*)d_ws;
  float* QW   = ws + OFF_QW;
  float* QO   = ws + OFF_QO;
  float* Wf   = ws + OFF_WF;
  float* qb   = ws + OFF_QB;
  float* bvo  = ws + OFF_BVO;
  int*   starts = (int*)(ws + OFF_STARTS);
  float* asum = ws + OFF_ASUM;
  float* WQT  = ws + OFF_WQT;
  float* WOT  = ws + OFF_WOT;
  float* Gp   = ws + OFF_GP;

  float* out     = (float*)d_out;                 // [64][64][256]
  float* out_arg = out + 64 * 64 * 256;           // [64][4096]
  float* out_msk = out_arg + 64 * MAXL;           // [64][4096]

  hipMemsetAsync(asum, 0, 64 * 64 * sizeof(float), stream);
  hipMemsetAsync(out_arg, 0, (size_t)2 * 64 * MAXL * sizeof(float), stream);

  k_tr<<<dim3(8, 8, 2), 256, 0, stream>>>(WQ_w, WO_w, WQT, WOT);
  k_prep<<<321, 1024, 0, stream>>>(Qp, WQT, WQ_b, WK_w, WK_b, WOT,
                                   WO_w, WV_w, WV_b, batch,
                                   QW, QO, qb, Wf, bvo, starts);

  k_fused<<<dim3(NP, 64), 512, 0, stream>>>(x, starts, QW, qb, Gp, asum,
                                            out_arg, out_msk);
  k_final<<<64 * 4, 256, 0, stream>>>(Gp, NP, Wf, QO, asum, bvo, WO_b, out);
}